// Round 1
// baseline (23947.102 us; speedup 1.0000x reference)
//
#include <hip/hip_runtime.h>
#include <cmath>

typedef __bf16 bf16x8 __attribute__((ext_vector_type(8)));
typedef float  f32x4  __attribute__((ext_vector_type(4)));

#define T_STEPS 1024
#define I_DIM   256
#define H_DIM   512
#define B_TOT   64
#define NBT     4     // batch tiles
#define NCT     32    // column tiles
#define BT      16    // batches per tile
#define CT      16    // columns per gate per WG

__device__ __forceinline__ f32x4 mfma16(bf16x8 a, bf16x8 b, f32x4 c) {
    return __builtin_amdgcn_mfma_f32_16x16x32_bf16(a, b, c, 0, 0, 0);
}

// load 8 consecutive f32 and convert to a bf16x8 A-fragment
__device__ __forceinline__ bf16x8 cvt8(const float* p) {
    float4 a = *(const float4*)p;
    float4 b = *(const float4*)(p + 4);
    bf16x8 f;
    f[0] = (__bf16)a.x; f[1] = (__bf16)a.y; f[2] = (__bf16)a.z; f[3] = (__bf16)a.w;
    f[4] = (__bf16)b.x; f[5] = (__bf16)b.y; f[6] = (__bf16)b.z; f[7] = (__bf16)b.w;
    return f;
}

// Persistent GRU kernel.
// Grid: 128 WGs = NBT(4) batch-tiles x NCT(32) column-tiles, 256 threads (4 waves).
// WG (i,j): batches [16i,16i+16), gate columns [16j,16j+16) of each of z/r/h.
// Wave w owns K-steps kk = w + 4*s (s=0..5) of K=768 ([x(256); h(512)]).
// s=0,1 are x-rows (no recurrence dep, issued before the flag wait); s=2..5 are h-rows.
__global__ __launch_bounds__(256, 1) void gru_persist(
    const float* __restrict__ xs,
    const float* __restrict__ Wz, const float* __restrict__ bz,
    const float* __restrict__ Wr, const float* __restrict__ br,
    const float* __restrict__ Wh, const float* __restrict__ bh,
    float* __restrict__ out,
    __bf16* hbuf, __bf16* rhbuf, int* flag_h, int* flag_r)
{
    const int bid  = blockIdx.x;
    const int i    = bid & (NBT - 1);   // same-i WGs land on 2 XCDs if XCD = bid%8
    const int j    = bid >> 2;
    const int tid  = threadIdx.x;
    const int w    = tid >> 6;
    const int lane = tid & 63;
    const int q    = lane >> 4;
    const int ln   = lane & 15;
    const int cb   = j * CT;

    __shared__ float red1[2][4][16][17];  // z/r partial tiles per wave (+1 pad)
    __shared__ float red2[4][16][17];     // h~ partials
    __shared__ float z_lds[16][17];
    __shared__ int   bail;
    if (tid == 0) bail = 0;
    __syncthreads();

    // ---- stationary weight B-fragments (bf16), loaded once ----
    // B layout for mfma_f32_16x16x32_bf16: B[k = q*8+jj][n = lane&15] per K-step.
    bf16x8 BZ[6], BR[6], BH[6];
    #pragma unroll
    for (int s = 0; s < 6; ++s) {
        int kk = w + 4 * s;
        int krow = kk * 32 + q * 8;
        bf16x8 fz, fr, fh;
        #pragma unroll
        for (int jj = 0; jj < 8; ++jj) {
            int off = (krow + jj) * H_DIM + cb + ln;
            fz[jj] = (__bf16)Wz[off];
            fr[jj] = (__bf16)Wr[off];
            fh[jj] = (__bf16)Wh[off];
        }
        BZ[s] = fz; BR[s] = fr; BH[s] = fh;
    }

    const int m = tid >> 4;   // epilogue thread -> (batch row m, col c)
    const int c = tid & 15;
    const float bzc = bz[cb + c], brc = br[cb + c], bhc = bh[cb + c];
    float hprev = 0.0f;       // f32 recurrent state owned by this thread

    const float* xrow = xs + (size_t)(i * BT + ln) * T_STEPS * I_DIM;
    const int HB_P = NBT * BT * H_DIM;   // 32768 elems per parity

    for (int t = 0; t < T_STEPS; ++t) {
        const int p = t & 1, pp = p ^ 1;
        f32x4 accz = {0,0,0,0}, accr = {0,0,0,0}, acch = {0,0,0,0};

        // ---- x-part MFMAs: independent of recurrence, issued before the wait ----
        const float* xt = xrow + (size_t)t * I_DIM;
        #pragma unroll
        for (int s = 0; s < 2; ++s) {
            int kk = w + 4 * s;
            bf16x8 ax = cvt8(xt + kk * 32 + q * 8);
            accz = mfma16(ax, BZ[s], accz);
            accr = mfma16(ax, BR[s], accr);
            acch = mfma16(ax, BH[s], acch);
        }

        // ---- wait for h_{t-1} (per-wave acquire poll) ----
        if (t > 0 && lane == 0) {
            int g = 0;
            while (*(volatile int*)&bail == 0 &&
                   __hip_atomic_load(&flag_h[(t-1)*NBT + i], __ATOMIC_ACQUIRE,
                                     __HIP_MEMORY_SCOPE_AGENT) < NCT) {
                if (++g > (1 << 25)) { *(volatile int*)&bail = 1; }
            }
        }

        // ---- stage 1: h-part MFMAs for z and r ----
        const __bf16* hb = hbuf + pp * HB_P + i * (BT * H_DIM) + ln * H_DIM;
        #pragma unroll
        for (int s = 2; s < 6; ++s) {
            int kk = w + 4 * s;                         // in [8,24)
            bf16x8 ah = *(const bf16x8*)(hb + (kk - 8) * 32 + q * 8);
            accz = mfma16(ah, BZ[s], accz);
            accr = mfma16(ah, BR[s], accr);
        }

        #pragma unroll
        for (int r4 = 0; r4 < 4; ++r4) {
            red1[0][w][q*4 + r4][ln] = accz[r4];        // C/D: row=q*4+r4, col=ln
            red1[1][w][q*4 + r4][ln] = accr[r4];
        }
        __syncthreads();

        float pz = red1[0][0][m][c] + red1[0][1][m][c] + red1[0][2][m][c] + red1[0][3][m][c] + bzc;
        float pr = red1[1][0][m][c] + red1[1][1][m][c] + red1[1][2][m][c] + red1[1][3][m][c] + brc;
        float zv = 1.0f / (1.0f + __expf(-pz));
        float rv = 1.0f / (1.0f + __expf(-pr));
        z_lds[m][c] = zv;
        rhbuf[p * HB_P + i * (BT * H_DIM) + m * H_DIM + cb + c] = (__bf16)(rv * hprev);
        __syncthreads();
        if (tid == 0)
            __hip_atomic_fetch_add(&flag_r[t*NBT + i], 1, __ATOMIC_RELEASE,
                                   __HIP_MEMORY_SCOPE_AGENT);

        // ---- wait for full r ⊙ h ----
        if (lane == 0) {
            int g = 0;
            while (*(volatile int*)&bail == 0 &&
                   __hip_atomic_load(&flag_r[t*NBT + i], __ATOMIC_ACQUIRE,
                                     __HIP_MEMORY_SCOPE_AGENT) < NCT) {
                if (++g > (1 << 25)) { *(volatile int*)&bail = 1; }
            }
        }

        // ---- stage 2: (r⊙h)-part MFMAs for h~ ----
        const __bf16* rb = rhbuf + p * HB_P + i * (BT * H_DIM) + ln * H_DIM;
        #pragma unroll
        for (int s = 2; s < 6; ++s) {
            int kk = w + 4 * s;
            bf16x8 ar = *(const bf16x8*)(rb + (kk - 8) * 32 + q * 8);
            acch = mfma16(ar, BH[s], acch);
        }

        #pragma unroll
        for (int r4 = 0; r4 < 4; ++r4)
            red2[w][q*4 + r4][ln] = acch[r4];
        __syncthreads();

        float ph  = red2[0][m][c] + red2[1][m][c] + red2[2][m][c] + red2[3][m][c] + bhc;
        float e2  = __expf(2.0f * ph);                 // tanh, safe: |ph| <~ 25
        float htl = (e2 - 1.0f) / (e2 + 1.0f);
        float zv2 = z_lds[m][c];
        float hn  = (1.0f - zv2) * hprev + zv2 * htl;
        hprev = hn;

        int bglob = i * BT + m;
        out[((size_t)bglob * T_STEPS + t) * H_DIM + cb + c] = hn;
        if (t == T_STEPS - 1)
            out[(size_t)B_TOT * T_STEPS * H_DIM + (size_t)bglob * H_DIM + cb + c] = hn;
        hbuf[p * HB_P + i * (BT * H_DIM) + m * H_DIM + cb + c] = (__bf16)hn;
        __syncthreads();
        if (tid == 0)
            __hip_atomic_fetch_add(&flag_h[t*NBT + i], 1, __ATOMIC_RELEASE,
                                   __HIP_MEMORY_SCOPE_AGENT);
    }
}

extern "C" void kernel_launch(void* const* d_in, const int* in_sizes, int n_in,
                              void* d_out, int out_size, void* d_ws, size_t ws_size,
                              hipStream_t stream)
{
    const float* xs = (const float*)d_in[0];
    const float* Wz = (const float*)d_in[1];
    const float* bz = (const float*)d_in[2];
    const float* Wr = (const float*)d_in[3];
    const float* br = (const float*)d_in[4];
    const float* Wh = (const float*)d_in[5];
    const float* bh = (const float*)d_in[6];
    float* out = (float*)d_out;

    // ws layout: hbuf[2][4][16][512] bf16 (128KB) | rhbuf same (128KB) |
    //            flag_h[1024*4] int (16KB) | flag_r[1024*4] int (16KB)
    __bf16* hbuf  = (__bf16*)d_ws;
    __bf16* rhbuf = hbuf + 2 * NBT * BT * H_DIM;
    int* flag_h = (int*)((char*)d_ws + 262144);
    int* flag_r = flag_h + T_STEPS * NBT;

    hipMemsetAsync(d_ws, 0, 294912, stream);   // zero h0, rh, and all flags
    gru_persist<<<dim3(NBT * NCT), dim3(256), 0, stream>>>(
        xs, Wz, bz, Wr, br, Wh, bh, out, hbuf, rhbuf, flag_h, flag_r);
}

// Round 2
// 6441.029 us; speedup vs baseline: 3.7179x; 3.7179x over previous
//
#include <hip/hip_runtime.h>
#include <cmath>

typedef __bf16 bf16x8 __attribute__((ext_vector_type(8)));
typedef float  f32x4  __attribute__((ext_vector_type(4)));
typedef unsigned long long u64;
typedef u64 u64x2 __attribute__((ext_vector_type(2)));

#define T_STEPS 1024
#define I_DIM   256
#define H_DIM   512
#define B_TOT   64
#define NBT     4     // batch tiles
#define NCT     32    // column tiles
#define BT      16    // batches per tile
#define CT      16    // columns per gate per WG
#define FPAD    16    // ints per flag slot (64B line)

__device__ __forceinline__ f32x4 mfma16(bf16x8 a, bf16x8 b, f32x4 c) {
    return __builtin_amdgcn_mfma_f32_16x16x32_bf16(a, b, c, 0, 0, 0);
}

// 8 consecutive f32 -> bf16x8 A-fragment (plain cached loads; xs is read-only)
__device__ __forceinline__ bf16x8 cvt8(const float* p) {
    float4 a = *(const float4*)p;
    float4 b = *(const float4*)(p + 4);
    bf16x8 f;
    f[0] = (__bf16)a.x; f[1] = (__bf16)a.y; f[2] = (__bf16)a.z; f[3] = (__bf16)a.w;
    f[4] = (__bf16)b.x; f[5] = (__bf16)b.y; f[6] = (__bf16)b.z; f[7] = (__bf16)b.w;
    return f;
}

// relaxed agent-scope primitives: sc0+sc1 (operate at LLC), NO buffer_inv/wbl2
__device__ __forceinline__ int ld_flag(const int* p) {
    return __hip_atomic_load(p, __ATOMIC_RELAXED, __HIP_MEMORY_SCOPE_AGENT);
}
__device__ __forceinline__ void st_flag(int* p, int v) {
    __hip_atomic_store(p, v, __ATOMIC_RELAXED, __HIP_MEMORY_SCOPE_AGENT);
}
__device__ __forceinline__ void st_u32(unsigned* p, unsigned v) {
    __hip_atomic_store(p, v, __ATOMIC_RELAXED, __HIP_MEMORY_SCOPE_AGENT);
}
// 16B bf16 fragment from LLC as two relaxed b64 atomic loads
__device__ __forceinline__ bf16x8 ld_frag16(const __bf16* p) {
    u64x2 v;
    v.x = __hip_atomic_load((const u64*)p,     __ATOMIC_RELAXED, __HIP_MEMORY_SCOPE_AGENT);
    v.y = __hip_atomic_load((const u64*)p + 1, __ATOMIC_RELAXED, __HIP_MEMORY_SCOPE_AGENT);
    return __builtin_bit_cast(bf16x8, v);
}

// wait until all 128 per-wave flags of this domain reach target.
// 64 lanes x 2 flags each, parallel relaxed polls + ballot. No cache ops.
__device__ __forceinline__ void wait128(const int* fb, int target) {
    const int l = threadIdx.x & 63;
    const int* p0 = fb + l * FPAD;
    const int* p1 = fb + (l + 64) * FPAD;
    for (int g = 0; g < (1 << 22); ++g) {
        int a = ld_flag(p0);
        int b = ld_flag(p1);
        if (__ballot(a >= target && b >= target) == ~0ull) break;
    }
    asm volatile("" ::: "memory");   // keep data loads below the poll
}

// wave-local drain of outstanding vmem stores (vmcnt(0), ignore exp/lgkm)
__device__ __forceinline__ void drain_stores() {
    __builtin_amdgcn_s_waitcnt(0x0f70);
}

// Persistent GRU. Grid: 128 WGs = 4 batch-tiles x 32 column-tiles, 256 thr (4 waves).
// Wave w owns K-steps kk = w + 4*s (s=0..5) of K=768 ([x(256); h(512)]).
__global__ __launch_bounds__(256, 1) void gru_persist(
    const float* __restrict__ xs,
    const float* __restrict__ Wz, const float* __restrict__ bz,
    const float* __restrict__ Wr, const float* __restrict__ br,
    const float* __restrict__ Wh, const float* __restrict__ bh,
    float* __restrict__ out,
    __bf16* hbuf, __bf16* rhbuf, int* flag_h, int* flag_r)
{
    const int bid  = blockIdx.x;
    const int i    = bid & (NBT - 1);
    const int j    = bid >> 2;
    const int tid  = threadIdx.x;
    const int w    = tid >> 6;
    const int lane = tid & 63;
    const int q    = lane >> 4;
    const int ln   = lane & 15;
    const int cb   = j * CT;

    __shared__ float red1[2][4][16][17];
    __shared__ float red2[4][16][17];
    __shared__ float z_lds[16][17];

    // ---- stationary weight B-fragments: B[k=q*8+jj][n=ln] per K-step ----
    bf16x8 BZ[6], BR[6], BH[6];
    #pragma unroll
    for (int s = 0; s < 6; ++s) {
        int kk = w + 4 * s;
        int krow = kk * 32 + q * 8;
        bf16x8 fz, fr, fh;
        #pragma unroll
        for (int jj = 0; jj < 8; ++jj) {
            int off = (krow + jj) * H_DIM + cb + ln;
            fz[jj] = (__bf16)Wz[off];
            fr[jj] = (__bf16)Wr[off];
            fh[jj] = (__bf16)Wh[off];
        }
        BZ[s] = fz; BR[s] = fr; BH[s] = fh;
    }

    const int m = tid >> 4;       // epilogue thread -> (batch m, col c)
    const int c = tid & 15;
    const float bzc = bz[cb + c], brc = br[cb + c], bhc = bh[cb + c];
    float hprev = 0.0f;           // f32 recurrent state per thread

    const float* xrow = xs + (size_t)(i * BT + ln) * T_STEPS * I_DIM;
    const int HB_P = NBT * BT * H_DIM;          // 32768 bf16 per parity
    int* fh_dom = flag_h + i * (NCT * 4) * FPAD;
    int* fr_dom = flag_r + i * (NCT * 4) * FPAD;
    int* my_fh  = fh_dom + (j * 4 + w) * FPAD;
    int* my_fr  = fr_dom + (j * 4 + w) * FPAD;

    for (int t = 0; t < T_STEPS; ++t) {
        const int p = t & 1, pp = p ^ 1;
        f32x4 accz = {0,0,0,0}, accr = {0,0,0,0}, acch = {0,0,0,0};

        // x-part MFMAs (no recurrence dep) before the wait
        const float* xt = xrow + (size_t)t * I_DIM;
        #pragma unroll
        for (int s = 0; s < 2; ++s) {
            int kk = w + 4 * s;
            bf16x8 ax = cvt8(xt + kk * 32 + q * 8);
            accz = mfma16(ax, BZ[s], accz);
            accr = mfma16(ax, BR[s], accr);
            acch = mfma16(ax, BH[s], acch);
        }

        // wait for h_{t-1}
        if (t > 0) wait128(fh_dom, t);

        // stage 1: h-part MFMAs for z and r (fragments straight from LLC)
        const __bf16* hb = hbuf + pp * HB_P + i * (BT * H_DIM) + ln * H_DIM;
        #pragma unroll
        for (int s = 2; s < 6; ++s) {
            int kk = w + 4 * s;
            bf16x8 ah = ld_frag16(hb + (kk - 8) * 32 + q * 8);
            accz = mfma16(ah, BZ[s], accz);
            accr = mfma16(ah, BR[s], accr);
        }

        #pragma unroll
        for (int r4 = 0; r4 < 4; ++r4) {
            red1[0][w][q*4 + r4][ln] = accz[r4];
            red1[1][w][q*4 + r4][ln] = accr[r4];
        }
        __syncthreads();                                         // S1

        // stage-1 epilogue: z, r, publish r*h (wave-local publish path)
        {
            float pz = red1[0][0][m][c] + red1[0][1][m][c] + red1[0][2][m][c] + red1[0][3][m][c] + bzc;
            float pr = red1[1][0][m][c] + red1[1][1][m][c] + red1[1][2][m][c] + red1[1][3][m][c] + brc;
            float zv = 1.0f / (1.0f + __expf(-pz));
            float rv = 1.0f / (1.0f + __expf(-pr));
            z_lds[m][c] = zv;                                    // same-thread reuse in stage 2
            unsigned short v16 = __builtin_bit_cast(unsigned short, (__bf16)(rv * hprev));
            unsigned short nb  = (unsigned short)__shfl((int)v16, lane + 1);
            if (!(c & 1)) {
                unsigned pkd = (unsigned)v16 | ((unsigned)nb << 16);
                st_u32((unsigned*)(rhbuf + p * HB_P + i * (BT * H_DIM) + m * H_DIM + cb + c), pkd);
            }
            drain_stores();                                      // wave-local vmcnt(0)
            if (lane == 0) st_flag(my_fr, t + 1);
        }

        // wait for full r⊙h
        wait128(fr_dom, t + 1);

        // stage 2: (r⊙h)-part MFMAs for h~
        const __bf16* rb = rhbuf + p * HB_P + i * (BT * H_DIM) + ln * H_DIM;
        #pragma unroll
        for (int s = 2; s < 6; ++s) {
            int kk = w + 4 * s;
            bf16x8 ar = ld_frag16(rb + (kk - 8) * 32 + q * 8);
            acch = mfma16(ar, BH[s], acch);
        }

        #pragma unroll
        for (int r4 = 0; r4 < 4; ++r4)
            red2[w][q*4 + r4][ln] = acch[r4];
        __syncthreads();                                         // S2

        // stage-2 epilogue: h~, h_t, publish h (wave-local publish path)
        {
            float ph  = red2[0][m][c] + red2[1][m][c] + red2[2][m][c] + red2[3][m][c] + bhc;
            float e2  = __expf(2.0f * ph);
            float htl = (e2 - 1.0f) / (e2 + 1.0f);
            float zv2 = z_lds[m][c];
            float hn  = (1.0f - zv2) * hprev + zv2 * htl;
            hprev = hn;

            int bglob = i * BT + m;
            out[((size_t)bglob * T_STEPS + t) * H_DIM + cb + c] = hn;
            if (t == T_STEPS - 1)
                out[(size_t)B_TOT * T_STEPS * H_DIM + (size_t)bglob * H_DIM + cb + c] = hn;

            unsigned short v16 = __builtin_bit_cast(unsigned short, (__bf16)hn);
            unsigned short nb  = (unsigned short)__shfl((int)v16, lane + 1);
            if (!(c & 1)) {
                unsigned pkd = (unsigned)v16 | ((unsigned)nb << 16);
                st_u32((unsigned*)(hbuf + p * HB_P + i * (BT * H_DIM) + m * H_DIM + cb + c), pkd);
            }
            drain_stores();
            if (lane == 0) st_flag(my_fh, t + 1);
        }
        // no further __syncthreads needed: LDS hazards are covered by S1/S2 of
        // the next iteration (red1/red2 reads happen before the next writes).
    }
}

extern "C" void kernel_launch(void* const* d_in, const int* in_sizes, int n_in,
                              void* d_out, int out_size, void* d_ws, size_t ws_size,
                              hipStream_t stream)
{
    const float* xs = (const float*)d_in[0];
    const float* Wz = (const float*)d_in[1];
    const float* bz = (const float*)d_in[2];
    const float* Wr = (const float*)d_in[3];
    const float* br = (const float*)d_in[4];
    const float* Wh = (const float*)d_in[5];
    const float* bh = (const float*)d_in[6];
    float* out = (float*)d_out;

    // ws: hbuf[2][4][16][512] bf16 (128KB) | rhbuf (128KB) |
    //     flag_h[4][32][4][16] int (32KB)  | flag_r (32KB)
    __bf16* hbuf  = (__bf16*)d_ws;
    __bf16* rhbuf = hbuf + 2 * NBT * BT * H_DIM;
    int* flag_h = (int*)((char*)d_ws + 262144);
    int* flag_r = flag_h + NBT * NCT * 4 * FPAD;

    hipMemsetAsync(d_ws, 0, 262144 + 2 * NBT * NCT * 4 * FPAD * 4, stream);
    gru_persist<<<dim3(NBT * NCT), dim3(256), 0, stream>>>(
        xs, Wz, bz, Wr, br, Wh, bh, out, hbuf, rhbuf, flag_h, flag_r);
}

// Round 3
// 6138.367 us; speedup vs baseline: 3.9012x; 1.0493x over previous
//
#include <hip/hip_runtime.h>
#include <cmath>

typedef __bf16 bf16x8 __attribute__((ext_vector_type(8)));
typedef float  f32x4  __attribute__((ext_vector_type(4)));
typedef unsigned long long u64;
typedef u64 u64x2 __attribute__((ext_vector_type(2)));

#define T_STEPS 1024
#define I_DIM   256
#define H_DIM   512
#define B_TOT   64
#define NBT     4     // batch tiles
#define NCT     32    // column tiles
#define BT      16    // batches per tile
#define CT      16    // columns per gate per WG
#define FDOM    64    // ints per flag domain (256B; 32 used, one 128B line)

__device__ __forceinline__ f32x4 mfma16(bf16x8 a, bf16x8 b, f32x4 c) {
    return __builtin_amdgcn_mfma_f32_16x16x32_bf16(a, b, c, 0, 0, 0);
}

// two float4 registers -> bf16x8 A-fragment (pure VALU, no loads)
__device__ __forceinline__ bf16x8 cvt8r(float4 a, float4 b) {
    bf16x8 f;
    f[0] = (__bf16)a.x; f[1] = (__bf16)a.y; f[2] = (__bf16)a.z; f[3] = (__bf16)a.w;
    f[4] = (__bf16)b.x; f[5] = (__bf16)b.y; f[6] = (__bf16)b.z; f[7] = (__bf16)b.w;
    return f;
}

// relaxed agent-scope primitives (operate at LLC, no buffer_inv/wbl2)
__device__ __forceinline__ int ld_flag(const int* p) {
    return __hip_atomic_load(p, __ATOMIC_RELAXED, __HIP_MEMORY_SCOPE_AGENT);
}
__device__ __forceinline__ void st_flag(int* p, int v) {
    __hip_atomic_store(p, v, __ATOMIC_RELAXED, __HIP_MEMORY_SCOPE_AGENT);
}
__device__ __forceinline__ void st_u32(unsigned* p, unsigned v) {
    __hip_atomic_store(p, v, __ATOMIC_RELAXED, __HIP_MEMORY_SCOPE_AGENT);
}
__device__ __forceinline__ bf16x8 ld_frag16(const __bf16* p) {
    u64x2 v;
    v.x = __hip_atomic_load((const u64*)p,     __ATOMIC_RELAXED, __HIP_MEMORY_SCOPE_AGENT);
    v.y = __hip_atomic_load((const u64*)p + 1, __ATOMIC_RELAXED, __HIP_MEMORY_SCOPE_AGENT);
    return __builtin_bit_cast(bf16x8, v);
}

// wait until all 32 per-WG flags of this domain (one 128B line) reach target
__device__ __forceinline__ void wait32(const int* fdom, int target) {
    const int* p = fdom + (threadIdx.x & 31);
    for (int g = 0; g < (1 << 22); ++g) {
        int v = ld_flag(p);
        if (__ballot(v >= target) == ~0ull) break;
    }
    asm volatile("" ::: "memory");   // keep data loads below the poll
}

// wave-local drain of outstanding vmem (vmcnt(0))
__device__ __forceinline__ void drain_vm() {
    __builtin_amdgcn_s_waitcnt(0x0f70);
}

// Persistent GRU. Grid: 128 WGs = 4 batch-tiles x 32 column-tiles, 256 thr (4 waves).
// Wave w owns K-steps kk = w + 4*s (s=0..5) of K=768 ([x(256); h(512)]).
__global__ __launch_bounds__(256, 1) void gru_persist(
    const float* __restrict__ xs,
    const float* __restrict__ Wz, const float* __restrict__ bz,
    const float* __restrict__ Wr, const float* __restrict__ br,
    const float* __restrict__ Wh, const float* __restrict__ bh,
    float* __restrict__ out,
    __bf16* hbuf, __bf16* rhbuf, int* flag_h, int* flag_r)
{
    const int bid  = blockIdx.x;
    const int i    = bid & (NBT - 1);
    const int j    = bid >> 2;
    const int tid  = threadIdx.x;
    const int w    = tid >> 6;
    const int lane = tid & 63;
    const int q    = lane >> 4;
    const int ln   = lane & 15;
    const int cb   = j * CT;

    __shared__ float red1[2][4][16][17];
    __shared__ float red2[4][16][17];
    __shared__ float z_lds[16][17];

    // ---- stationary weight B-fragments: B[k=q*8+jj][n=ln] per K-step ----
    bf16x8 BZ[6], BR[6], BH[6];
    #pragma unroll
    for (int s = 0; s < 6; ++s) {
        int kk = w + 4 * s;
        int krow = kk * 32 + q * 8;
        bf16x8 fz, fr, fh;
        #pragma unroll
        for (int jj = 0; jj < 8; ++jj) {
            int off = (krow + jj) * H_DIM + cb + ln;
            fz[jj] = (__bf16)Wz[off];
            fr[jj] = (__bf16)Wr[off];
            fh[jj] = (__bf16)Wh[off];
        }
        BZ[s] = fz; BR[s] = fr; BH[s] = fh;
    }

    const int m = tid >> 4;       // epilogue thread -> (batch m, col c)
    const int c = tid & 15;
    const float bzc = bz[cb + c], brc = br[cb + c], bhc = bh[cb + c];
    float hprev = 0.0f;

    const float* xrow = xs + (size_t)(i * BT + ln) * T_STEPS * I_DIM;
    const int HB_P = NBT * BT * H_DIM;          // 32768 bf16 per parity
    int* fh_dom = flag_h + i * FDOM;
    int* fr_dom = flag_r + i * FDOM;
    int* my_fh  = fh_dom + j;
    int* my_fr  = fr_dom + j;

    // x fragments for current step held in registers (loaded one step ahead)
    float4 xr[4];                 // s=0: xr[0],xr[1]; s=1: xr[2],xr[3]
    {
        const float* x0 = xrow;   // t = 0
        xr[0] = *(const float4*)(x0 + (w    ) * 32 + q * 8);
        xr[1] = *(const float4*)(x0 + (w    ) * 32 + q * 8 + 4);
        xr[2] = *(const float4*)(x0 + (w + 4) * 32 + q * 8);
        xr[3] = *(const float4*)(x0 + (w + 4) * 32 + q * 8 + 4);
    }

    for (int t = 0; t < T_STEPS; ++t) {
        const int p = t & 1, pp = p ^ 1;

        // ---- issue prefetch of x for step t+1 (retires during this step) ----
        float4 xn[4];
        {
            int tn = (t + 1 < T_STEPS) ? t + 1 : t;
            const float* xp = xrow + (size_t)tn * I_DIM;
            xn[0] = *(const float4*)(xp + (w    ) * 32 + q * 8);
            xn[1] = *(const float4*)(xp + (w    ) * 32 + q * 8 + 4);
            xn[2] = *(const float4*)(xp + (w + 4) * 32 + q * 8);
            xn[3] = *(const float4*)(xp + (w + 4) * 32 + q * 8 + 4);
        }

        f32x4 accz = {0,0,0,0}, accr = {0,0,0,0}, acch = {0,0,0,0};

        // x-part MFMAs from registers (no loads, no recurrence dep)
        {
            bf16x8 ax0 = cvt8r(xr[0], xr[1]);
            bf16x8 ax1 = cvt8r(xr[2], xr[3]);
            accz = mfma16(ax0, BZ[0], accz);
            accr = mfma16(ax0, BR[0], accr);
            acch = mfma16(ax0, BH[0], acch);
            accz = mfma16(ax1, BZ[1], accz);
            accr = mfma16(ax1, BR[1], accr);
            acch = mfma16(ax1, BH[1], acch);
        }

        // ---- wait for h_{t-1} (single-line poll) ----
        if (t > 0) wait32(fh_dom, t);

        // stage 1: h-part MFMAs for z and r
        const __bf16* hb = hbuf + pp * HB_P + i * (BT * H_DIM) + ln * H_DIM;
        #pragma unroll
        for (int s = 2; s < 6; ++s) {
            int kk = w + 4 * s;
            bf16x8 ah = ld_frag16(hb + (kk - 8) * 32 + q * 8);
            accz = mfma16(ah, BZ[s], accz);
            accr = mfma16(ah, BR[s], accr);
        }

        #pragma unroll
        for (int r4 = 0; r4 < 4; ++r4) {
            red1[0][w][q*4 + r4][ln] = accz[r4];
            red1[1][w][q*4 + r4][ln] = accr[r4];
        }
        __syncthreads();                                         // S1

        // stage-1 epilogue: z, r, publish r*h
        {
            float pz = red1[0][0][m][c] + red1[0][1][m][c] + red1[0][2][m][c] + red1[0][3][m][c] + bzc;
            float pr = red1[1][0][m][c] + red1[1][1][m][c] + red1[1][2][m][c] + red1[1][3][m][c] + brc;
            float zv = 1.0f / (1.0f + __expf(-pz));
            float rv = 1.0f / (1.0f + __expf(-pr));
            z_lds[m][c] = zv;
            unsigned short v16 = __builtin_bit_cast(unsigned short, (__bf16)(rv * hprev));
            unsigned short nb  = (unsigned short)__shfl((int)v16, lane + 1);
            if (!(c & 1)) {
                unsigned pkd = (unsigned)v16 | ((unsigned)nb << 16);
                st_u32((unsigned*)(rhbuf + p * HB_P + i * (BT * H_DIM) + m * H_DIM + cb + c), pkd);
            }
            drain_vm();                                          // per-wave store drain
            __syncthreads();                                     // S1b: all waves drained
            if (tid == 0) st_flag(my_fr, t + 1);
        }

        // ---- wait for full r⊙h ----
        wait32(fr_dom, t + 1);

        // stage 2: (r⊙h)-part MFMAs for h~
        const __bf16* rb = rhbuf + p * HB_P + i * (BT * H_DIM) + ln * H_DIM;
        #pragma unroll
        for (int s = 2; s < 6; ++s) {
            int kk = w + 4 * s;
            bf16x8 ar = ld_frag16(rb + (kk - 8) * 32 + q * 8);
            acch = mfma16(ar, BH[s], acch);
        }

        #pragma unroll
        for (int r4 = 0; r4 < 4; ++r4)
            red2[w][q*4 + r4][ln] = acch[r4];
        __syncthreads();                                         // S2

        // stage-2 epilogue: h~, h_t, publish h; out[] stores AFTER the flag
        {
            float ph  = red2[0][m][c] + red2[1][m][c] + red2[2][m][c] + red2[3][m][c] + bhc;
            float e2  = __expf(2.0f * ph);
            float htl = (e2 - 1.0f) / (e2 + 1.0f);
            float zv2 = z_lds[m][c];
            float hn  = (1.0f - zv2) * hprev + zv2 * htl;
            hprev = hn;

            unsigned short v16 = __builtin_bit_cast(unsigned short, (__bf16)hn);
            unsigned short nb  = (unsigned short)__shfl((int)v16, lane + 1);
            if (!(c & 1)) {
                unsigned pkd = (unsigned)v16 | ((unsigned)nb << 16);
                st_u32((unsigned*)(hbuf + p * HB_P + i * (BT * H_DIM) + m * H_DIM + cb + c), pkd);
            }
            drain_vm();
            __syncthreads();                                     // S2b
            if (tid == 0) st_flag(my_fh, t + 1);

            // off-critical-path output stores (drained by next step's stage-1 drain)
            int bglob = i * BT + m;
            out[((size_t)bglob * T_STEPS + t) * H_DIM + cb + c] = hn;
            if (t == T_STEPS - 1)
                out[(size_t)B_TOT * T_STEPS * H_DIM + (size_t)bglob * H_DIM + cb + c] = hn;
        }

        // roll prefetched x into current
        xr[0] = xn[0]; xr[1] = xn[1]; xr[2] = xn[2]; xr[3] = xn[3];
    }
}

extern "C" void kernel_launch(void* const* d_in, const int* in_sizes, int n_in,
                              void* d_out, int out_size, void* d_ws, size_t ws_size,
                              hipStream_t stream)
{
    const float* xs = (const float*)d_in[0];
    const float* Wz = (const float*)d_in[1];
    const float* bz = (const float*)d_in[2];
    const float* Wr = (const float*)d_in[3];
    const float* br = (const float*)d_in[4];
    const float* Wh = (const float*)d_in[5];
    const float* bh = (const float*)d_in[6];
    float* out = (float*)d_out;

    // ws: hbuf[2][4][16][512] bf16 (128KB) | rhbuf (128KB) |
    //     flag_h[4][64] int (1KB) | flag_r[4][64] int (1KB)
    __bf16* hbuf  = (__bf16*)d_ws;
    __bf16* rhbuf = hbuf + 2 * NBT * BT * H_DIM;
    int* flag_h = (int*)((char*)d_ws + 262144);
    int* flag_r = flag_h + NBT * FDOM;

    hipMemsetAsync(d_ws, 0, 262144 + 2 * NBT * FDOM * 4, stream);
    gru_persist<<<dim3(NBT * NCT), dim3(256), 0, stream>>>(
        xs, Wz, bz, Wr, br, Wh, bh, out, hbuf, rhbuf, flag_h, flag_r);
}